// Round 1
// baseline (511.919 us; speedup 1.0000x reference)
//
#include <hip/hip_runtime.h>

#define BATCH 8
#define NTOK 1032
#define NPAD 1088
#define NHEAD 16
#define HD 64
#define MTOT (BATCH*NTOK)   // 8256

typedef __bf16 bf16x8 __attribute__((ext_vector_type(8)));
typedef float f32x4 __attribute__((ext_vector_type(4)));
typedef unsigned short us8 __attribute__((ext_vector_type(8)));
typedef unsigned short us4 __attribute__((ext_vector_type(4)));

__device__ __forceinline__ unsigned short f2bf(float f){
  unsigned int u = __builtin_bit_cast(unsigned int, f);
  u += 0x7fffu + ((u >> 16) & 1u);          // RNE
  return (unsigned short)(u >> 16);
}

#define MFMA16(a,b,c) __builtin_amdgcn_mfma_f32_16x16x32_bf16( \
    __builtin_bit_cast(bf16x8,(a)), __builtin_bit_cast(bf16x8,(b)), (c), 0, 0, 0)

// ---------------- fp32 -> bf16 conversion ----------------
__global__ __launch_bounds__(256) void cvt_f32_bf16(const float* __restrict__ in,
                                                    unsigned short* __restrict__ out, int n4){
  int i = blockIdx.x * 256 + threadIdx.x;
  if (i < n4){
    float4 v = reinterpret_cast<const float4*>(in)[i];
    us4 o; o.x = f2bf(v.x); o.y = f2bf(v.y); o.z = f2bf(v.z); o.w = f2bf(v.w);
    reinterpret_cast<us4*>(out)[i] = o;
  }
}

// ---------------- zero the padded rows (avoid NaN poison propagating) ----------------
__global__ __launch_bounds__(256) void pad_zero(unsigned short* __restrict__ qb,
                                                unsigned short* __restrict__ kb,
                                                unsigned short* __restrict__ vt){
  int i = blockIdx.x * 256 + threadIdx.x;
  const int total = 128 * (NPAD - NTOK) * 64;   // 128*56*64
  if (i < total){
    int bh = i / ((NPAD - NTOK) * 64);
    int r  = (i / 64) % (NPAD - NTOK);
    int d  = i % 64;
    int idx = (bh * NPAD + NTOK + r) * 64 + d;
    qb[idx] = 0;
    kb[idx] = 0;
    vt[(bh * 64 + d) * NPAD + NTOK + r] = 0;
  }
}

// ---------------- QKV GEMM: C[8256][3072] = A[8256][1024] * W[3072][1024]^T ----------------
__global__ __launch_bounds__(256,2) void qkv_gemm(
    const unsigned short* __restrict__ A,   // [MTOT][1024] bf16
    const unsigned short* __restrict__ Bw,  // [3072][1024] bf16
    const float* __restrict__ bias,         // [3072]
    unsigned short* __restrict__ qb,        // [128][NPAD][64]
    unsigned short* __restrict__ kb,        // [128][NPAD][64]
    unsigned short* __restrict__ vt)        // [128][64][NPAD]
{
  const int K = 1024;
  __shared__ __align__(16) unsigned short As[128][40];
  __shared__ __align__(16) unsigned short Bs[128][40];
  int tid = threadIdx.x;
  int m0 = blockIdx.y * 128, n0 = blockIdx.x * 128;
  int w = tid >> 6, lane = tid & 63, lr = lane & 15, lg = lane >> 4;
  int wr = w >> 1, wc = w & 1;
  f32x4 acc[4][4] = {};

  for (int k0 = 0; k0 < K; k0 += 32){
    __syncthreads();
    #pragma unroll
    for (int i = 0; i < 2; i++){
      int c = tid + i * 256;          // 512 chunks of 8 bf16
      int row = c >> 2, col = (c & 3) * 8;
      float4 va{};
      int gm = m0 + row;
      if (gm < MTOT) va = *reinterpret_cast<const float4*>(&A[(size_t)gm * K + k0 + col]);
      *reinterpret_cast<float4*>(&As[row][col]) = va;
      float4 vb = *reinterpret_cast<const float4*>(&Bw[(size_t)(n0 + row) * K + k0 + col]);
      *reinterpret_cast<float4*>(&Bs[row][col]) = vb;
    }
    __syncthreads();
    us8 a[4], b[4];
    #pragma unroll
    for (int mi = 0; mi < 4; mi++) a[mi] = *reinterpret_cast<const us8*>(&As[wr*64 + mi*16 + lr][lg*8]);
    #pragma unroll
    for (int ni = 0; ni < 4; ni++) b[ni] = *reinterpret_cast<const us8*>(&Bs[wc*64 + ni*16 + lr][lg*8]);
    #pragma unroll
    for (int mi = 0; mi < 4; mi++)
      #pragma unroll
      for (int ni = 0; ni < 4; ni++)
        acc[mi][ni] = MFMA16(a[mi], b[ni], acc[mi][ni]);
  }

  // epilogue: scatter into q/k [bh][n][64] and v transposed [bh][64][n]
  #pragma unroll
  for (int mi = 0; mi < 4; mi++){
    #pragma unroll
    for (int ni = 0; ni < 4; ni++){
      #pragma unroll
      for (int reg = 0; reg < 4; reg++){
        int m = m0 + wr*64 + mi*16 + lg*4 + reg;
        if (m >= MTOT) continue;
        int n = n0 + wc*64 + ni*16 + lr;
        float val = acc[mi][ni][reg] + bias[n];
        int b_ = m / NTOK, nidx = m % NTOK;
        int t = n >> 10, h = (n >> 6) & 15, d = n & 63;
        int bh = h * BATCH + b_;
        unsigned short bv = f2bf(val);
        if (t == 0)      qb[(size_t)(bh * NPAD + nidx) * 64 + d] = bv;
        else if (t == 1) kb[(size_t)(bh * NPAD + nidx) * 64 + d] = bv;
        else             vt[(size_t)(bh * 64 + d) * NPAD + nidx] = bv;
      }
    }
  }
}

// ---------------- flash attention with decomposed rel-pos ----------------
__global__ __launch_bounds__(256,2) void attn_kernel(
    const unsigned short* __restrict__ qb,
    const unsigned short* __restrict__ kb,
    const unsigned short* __restrict__ vt,
    const float* __restrict__ rph,   // [63][64]
    const float* __restrict__ rpw,   // [63][64]
    unsigned short* __restrict__ ao) // [8][1032][1024]
{
  __shared__ float RH[64][64];
  __shared__ float RW[64][64];
  __shared__ __align__(16) unsigned short Ps[4][16][72];

  int qt = blockIdx.x;          // 0..16
  int bh = blockIdx.y;          // 0..127
  int tid = threadIdx.x, w = tid >> 6, lane = tid & 63, lr = lane & 15, lg = lane >> 4;
  int h = bh >> 3, b_ = bh & 7;

  const unsigned short* qbase = qb + (size_t)bh * NPAD * 64;
  const unsigned short* kbase = kb + (size_t)bh * NPAD * 64;
  const unsigned short* vbase = vt + (size_t)bh * 64 * NPAD;

  // Q A-fragments (wave w owns q-rows [w*16, w*16+16) of the tile)
  int qrow_lane = qt * 64 + w * 16 + lr;
  us8 aq[2];
  aq[0] = *reinterpret_cast<const us8*>(&qbase[(size_t)qrow_lane * 64 + lg * 8]);
  aq[1] = *reinterpret_cast<const us8*>(&qbase[(size_t)qrow_lane * 64 + 32 + lg * 8]);

  // rel-pos tables RH[qrow][t] = dot(q, rel_pos_h[t]) (unscaled q), t in [0,63)
  if (qt < 16){
    f32x4 ah[4] = {}, aw[4] = {};
    #pragma unroll
    for (int ks = 0; ks < 2; ks++){
      #pragma unroll
      for (int nf = 0; nf < 4; nf++){
        int t = nf * 16 + lr;
        int c = ks * 32 + lg * 8;
        us8 bfh, bfw;
        #pragma unroll
        for (int j = 0; j < 8; j++){
          float vh = 0.f, vw = 0.f;
          if (t < 63){ vh = rph[t * 64 + c + j]; vw = rpw[t * 64 + c + j]; }
          bfh[j] = f2bf(vh);
          bfw[j] = f2bf(vw);
        }
        ah[nf] = MFMA16(aq[ks], bfh, ah[nf]);
        aw[nf] = MFMA16(aq[ks], bfw, aw[nf]);
      }
    }
    #pragma unroll
    for (int nf = 0; nf < 4; nf++)
      #pragma unroll
      for (int reg = 0; reg < 4; reg++){
        RH[w*16 + lg*4 + reg][nf*16 + lr] = ah[nf][reg];
        RW[w*16 + lg*4 + reg][nf*16 + lr] = aw[nf][reg];
      }
    // no barrier: each wave only reads rows it wrote
  }

  float m_run[4] = {-1e30f, -1e30f, -1e30f, -1e30f};
  float l_run[4] = {0.f, 0.f, 0.f, 0.f};
  f32x4 O[4] = {};

  for (int kt = 0; kt < 17; kt++){
    // S = Q @ K^T  (per wave: 16 q-rows x 64 keys)
    f32x4 S[4] = {};
    #pragma unroll
    for (int ks = 0; ks < 2; ks++){
      #pragma unroll
      for (int nf = 0; nf < 4; nf++){
        us8 bk = *reinterpret_cast<const us8*>(
            &kbase[(size_t)(kt*64 + nf*16 + lr) * 64 + ks*32 + lg*8]);
        S[nf] = MFMA16(aq[ks], bk, S[nf]);
      }
    }
    // logits = S*scale + rel bias, mask invalid keys
    float p[4][4];
    #pragma unroll
    for (int nf = 0; nf < 4; nf++){
      #pragma unroll
      for (int reg = 0; reg < 4; reg++){
        int key = kt*64 + nf*16 + lr;
        float s = S[nf][reg] * 0.125f;
        if (qt < 16 && key < 1024){
          int qrow = w*16 + lg*4 + reg;
          int qg = qt*64 + qrow;
          int idxh = (qg >> 5) - (key >> 5) + 31;
          int idxw = (qg & 31) - (key & 31) + 31;
          s += RH[qrow][idxh] + RW[qrow][idxw];
        }
        if (key >= NTOK) s = -1e30f;
        p[nf][reg] = s;
      }
    }
    // online softmax per q-row (rows = regs, spread over 16 lanes)
    #pragma unroll
    for (int reg = 0; reg < 4; reg++){
      float tm = fmaxf(fmaxf(p[0][reg], p[1][reg]), fmaxf(p[2][reg], p[3][reg]));
      #pragma unroll
      for (int off = 1; off < 16; off <<= 1) tm = fmaxf(tm, __shfl_xor(tm, off));
      float mnew = fmaxf(m_run[reg], tm);
      float alpha = __expf(m_run[reg] - mnew);
      float rs = 0.f;
      #pragma unroll
      for (int nf = 0; nf < 4; nf++){
        float pe = __expf(p[nf][reg] - mnew);
        p[nf][reg] = pe;
        rs += pe;
      }
      #pragma unroll
      for (int off = 1; off < 16; off <<= 1) rs += __shfl_xor(rs, off);
      l_run[reg] = l_run[reg] * alpha + rs;
      m_run[reg] = mnew;
      #pragma unroll
      for (int nfd = 0; nfd < 4; nfd++) O[nfd][reg] *= alpha;
    }
    // P: C-layout -> A-layout via per-wave LDS (bf16)
    #pragma unroll
    for (int nf = 0; nf < 4; nf++)
      #pragma unroll
      for (int reg = 0; reg < 4; reg++)
        Ps[w][lg*4 + reg][nf*16 + lr] = f2bf(p[nf][reg]);
    us8 pa[2];
    pa[0] = *reinterpret_cast<const us8*>(&Ps[w][lr][lg*8]);
    pa[1] = *reinterpret_cast<const us8*>(&Ps[w][lr][32 + lg*8]);
    // O += P @ V  (V transposed: [d][key])
    #pragma unroll
    for (int ks = 0; ks < 2; ks++){
      #pragma unroll
      for (int nfd = 0; nfd < 4; nfd++){
        us8 bv = *reinterpret_cast<const us8*>(
            &vbase[(size_t)(nfd*16 + lr) * NPAD + kt*64 + ks*32 + lg*8]);
        O[nfd] = MFMA16(pa[ks], bv, O[nfd]);
      }
    }
  }

  // epilogue: O /= l, write [b][n][h*64+d]
  #pragma unroll
  for (int reg = 0; reg < 4; reg++){
    float inv = 1.0f / l_run[reg];
    int qrow = w*16 + lg*4 + reg;
    int qg = qt*64 + qrow;
    if (qg < NTOK){
      #pragma unroll
      for (int nfd = 0; nfd < 4; nfd++){
        int d = nfd*16 + lr;
        ao[(size_t)(b_ * NTOK + qg) * 1024 + h * 64 + d] = f2bf(O[nfd][reg] * inv);
      }
    }
  }
}

// ---------------- proj GEMM: out[8256][1024] = A[8256][1024] * W[1024][1024]^T + b ----------------
__global__ __launch_bounds__(256,2) void proj_gemm(
    const unsigned short* __restrict__ A,
    const unsigned short* __restrict__ Bw,
    const float* __restrict__ bias,
    float* __restrict__ out)
{
  const int K = 1024;
  __shared__ __align__(16) unsigned short As[128][40];
  __shared__ __align__(16) unsigned short Bs[128][40];
  int tid = threadIdx.x;
  int m0 = blockIdx.y * 128, n0 = blockIdx.x * 128;
  int w = tid >> 6, lane = tid & 63, lr = lane & 15, lg = lane >> 4;
  int wr = w >> 1, wc = w & 1;
  f32x4 acc[4][4] = {};

  for (int k0 = 0; k0 < K; k0 += 32){
    __syncthreads();
    #pragma unroll
    for (int i = 0; i < 2; i++){
      int c = tid + i * 256;
      int row = c >> 2, col = (c & 3) * 8;
      float4 va{};
      int gm = m0 + row;
      if (gm < MTOT) va = *reinterpret_cast<const float4*>(&A[(size_t)gm * K + k0 + col]);
      *reinterpret_cast<float4*>(&As[row][col]) = va;
      float4 vb = *reinterpret_cast<const float4*>(&Bw[(size_t)(n0 + row) * K + k0 + col]);
      *reinterpret_cast<float4*>(&Bs[row][col]) = vb;
    }
    __syncthreads();
    us8 a[4], b[4];
    #pragma unroll
    for (int mi = 0; mi < 4; mi++) a[mi] = *reinterpret_cast<const us8*>(&As[wr*64 + mi*16 + lr][lg*8]);
    #pragma unroll
    for (int ni = 0; ni < 4; ni++) b[ni] = *reinterpret_cast<const us8*>(&Bs[wc*64 + ni*16 + lr][lg*8]);
    #pragma unroll
    for (int mi = 0; mi < 4; mi++)
      #pragma unroll
      for (int ni = 0; ni < 4; ni++)
        acc[mi][ni] = MFMA16(a[mi], b[ni], acc[mi][ni]);
  }

  #pragma unroll
  for (int mi = 0; mi < 4; mi++){
    #pragma unroll
    for (int ni = 0; ni < 4; ni++){
      #pragma unroll
      for (int reg = 0; reg < 4; reg++){
        int m = m0 + wr*64 + mi*16 + lg*4 + reg;
        if (m >= MTOT) continue;
        int n = n0 + wc*64 + ni*16 + lr;
        out[(size_t)m * 1024 + n] = acc[mi][ni][reg] + bias[n];
      }
    }
  }
}

extern "C" void kernel_launch(void* const* d_in, const int* in_sizes, int n_in,
                              void* d_out, int out_size, void* d_ws, size_t ws_size,
                              hipStream_t stream)
{
  const float* x      = (const float*)d_in[0];
  const float* qkv_w  = (const float*)d_in[1];
  const float* qkv_b  = (const float*)d_in[2];
  const float* proj_w = (const float*)d_in[3];
  const float* proj_b = (const float*)d_in[4];
  const float* rph    = (const float*)d_in[5];
  const float* rpw    = (const float*)d_in[6];
  float* out = (float*)d_out;

  char* ws = (char*)d_ws;
  size_t off = 0;
  auto alloc = [&](size_t bytes){ char* p = ws + off; off += (bytes + 255) & ~(size_t)255; return p; };
  unsigned short* x_bf  = (unsigned short*)alloc((size_t)MTOT * 1024 * 2);
  unsigned short* qw_bf = (unsigned short*)alloc((size_t)3072 * 1024 * 2);
  unsigned short* pw_bf = (unsigned short*)alloc((size_t)1024 * 1024 * 2);
  unsigned short* qbuf  = (unsigned short*)alloc((size_t)128 * NPAD * 64 * 2);
  unsigned short* kbuf  = (unsigned short*)alloc((size_t)128 * NPAD * 64 * 2);
  unsigned short* vtbuf = (unsigned short*)alloc((size_t)128 * 64 * NPAD * 2);
  unsigned short* aout  = (unsigned short*)alloc((size_t)MTOT * 1024 * 2);
  if (off > ws_size) return;   // workspace too small: fail visibly

  int n4x = MTOT * 1024 / 4;
  cvt_f32_bf16<<<dim3((n4x + 255) / 256), 256, 0, stream>>>(x, x_bf, n4x);
  int n4q = 3072 * 1024 / 4;
  cvt_f32_bf16<<<dim3((n4q + 255) / 256), 256, 0, stream>>>(qkv_w, qw_bf, n4q);
  int n4p = 1024 * 1024 / 4;
  cvt_f32_bf16<<<dim3((n4p + 255) / 256), 256, 0, stream>>>(proj_w, pw_bf, n4p);

  int npad = 128 * (NPAD - NTOK) * 64;
  pad_zero<<<dim3((npad + 255) / 256), 256, 0, stream>>>(qbuf, kbuf, vtbuf);

  qkv_gemm<<<dim3(24, 65), 256, 0, stream>>>(x_bf, qw_bf, qkv_b, qbuf, kbuf, vtbuf);
  attn_kernel<<<dim3(17, 128), 256, 0, stream>>>(qbuf, kbuf, vtbuf, rph, rpw, aout);
  proj_gemm<<<dim3(8, 65), 256, 0, stream>>>(aout, pw_bf, proj_b, out);
}